// Round 1
// baseline (19846.042 us; speedup 1.0000x reference)
//
#include <hip/hip_runtime.h>

// Problem dims (fixed by reference)
#define T_SEQ 512
#define B_SZ  64
#define IN_SZ 512
#define H_SZ  1024

typedef _Float16 f16;
typedef _Float16 half8 __attribute__((ext_vector_type(8)));
typedef float    f32x4 __attribute__((ext_vector_type(4)));

__device__ __forceinline__ float sigf(float x)     { return 1.f / (1.f + __expf(-x)); }
__device__ __forceinline__ float tanhfast(float x) { return 2.f / (1.f + __expf(-2.f * x)) - 1.f; }

// ---------------------------------------------------------------------------
// Convert weights fp32 -> fp16 and pre-sum biases. Runs every call (inputs are
// restored and ws re-poisoned before each timed launch).
// ---------------------------------------------------------------------------
__global__ void convert_kernel(
    const float* __restrict__ wih0, const float* __restrict__ whh0,
    const float* __restrict__ wih1, const float* __restrict__ whh1,
    const float* __restrict__ bih0, const float* __restrict__ bhh0,
    const float* __restrict__ bih1, const float* __restrict__ bhh1,
    f16* __restrict__ wih0h, f16* __restrict__ whh0h,
    f16* __restrict__ wih1h, f16* __restrict__ whh1h,
    float* __restrict__ bias0, float* __restrict__ bias1)
{
    const long N0 = 4096L * 512;   // w_ih0
    const long N1 = 4096L * 1024;  // each of w_hh0, w_ih1, w_hh1
    const long TOT = N0 + 3 * N1 + 8192;
    long stride = (long)gridDim.x * blockDim.x;
    for (long idx = (long)blockIdx.x * blockDim.x + threadIdx.x; idx < TOT; idx += stride) {
        long j = idx;
        if (j < N0) { wih0h[j] = (f16)wih0[j]; continue; } j -= N0;
        if (j < N1) { whh0h[j] = (f16)whh0[j]; continue; } j -= N1;
        if (j < N1) { wih1h[j] = (f16)wih1[j]; continue; } j -= N1;
        if (j < N1) { whh1h[j] = (f16)whh1[j]; continue; } j -= N1;
        if (j < 4096) { bias0[j] = bih0[j] + bhh0[j]; continue; } j -= 4096;
        bias1[j] = bih1[j] + bhh1[j];
    }
}

// ---------------------------------------------------------------------------
// One pipelined timestep: blocks 0..63 run layer 0 at t=s, blocks 64..127 run
// layer 1 at t=s-1. Each block owns a 16-wide h-slice (jb..jb+15) and computes
// all four gates for it over the full batch (M=64).
// Block = 512 threads = 8 waves = 4 gates x 2 k-halves.
// ---------------------------------------------------------------------------
__global__ __launch_bounds__(512) void step_kernel(
    const float* __restrict__ x,                                  // [B,T,IN] fp32
    const f16* __restrict__ wih0, const f16* __restrict__ whh0,
    const f16* __restrict__ wih1, const f16* __restrict__ whh1,
    const float* __restrict__ bias0, const float* __restrict__ bias1,
    f16* __restrict__ h1buf, f16* __restrict__ h2buf,             // [2][B,H] fp16
    float* __restrict__ c0, float* __restrict__ c1,               // [B,H] fp32
    f16* __restrict__ h2all,                                      // [T,B,H] fp16
    int s)
{
    const int layer = blockIdx.x >> 6;
    if (layer == 0 && s == T_SEQ) return;  // layer 0 done after s=511
    if (layer == 1 && s == 0)     return;  // layer 1 starts at s=1

    const int jb   = (blockIdx.x & 63) * 16;
    const int tid  = threadIdx.x;
    const int wave = tid >> 6, lane = tid & 63;
    const int g = wave & 3, p = wave >> 2;     // gate type, k-half
    const int q = lane >> 4, r16 = lane & 15;  // k-quad, row/col-in-tile

    const int cur = s & 1, prv = cur ^ 1;
    const f16* h1prev = h1buf + prv * (B_SZ * H_SZ);

    f32x4 acc[4] = {};

    const int n = g * H_SZ + jb + r16;         // gate row this lane loads (B side)

    if (layer == 0) {
        const f16* brow1 = wih0 + (size_t)n * IN_SZ;
        const f16* brow2 = whh0 + (size_t)n * H_SZ;
        // x part: K = 512 (fp32 loaded, converted in-register)
        #pragma unroll
        for (int it = 0; it < 8; ++it) {
            int k = p * 256 + it * 32 + q * 8;
            half8 bf = *(const half8*)(brow1 + k);
            #pragma unroll
            for (int mt = 0; mt < 4; ++mt) {
                const float* ar = x + (size_t)(mt * 16 + r16) * (T_SEQ * IN_SZ)
                                    + (size_t)s * IN_SZ + k;
                f32x4 xa = *(const f32x4*)ar;
                f32x4 xb = *(const f32x4*)(ar + 4);
                half8 af;
                #pragma unroll
                for (int u = 0; u < 4; ++u) { af[u] = (f16)xa[u]; af[4 + u] = (f16)xb[u]; }
                acc[mt] = __builtin_amdgcn_mfma_f32_16x16x32_f16(af, bf, acc[mt], 0, 0, 0);
            }
        }
        // h1 recurrent part: K = 1024
        #pragma unroll
        for (int it = 0; it < 16; ++it) {
            int k = p * 512 + it * 32 + q * 8;
            half8 bf = *(const half8*)(brow2 + k);
            #pragma unroll
            for (int mt = 0; mt < 4; ++mt) {
                half8 af = *(const half8*)(h1prev + (size_t)(mt * 16 + r16) * H_SZ + k);
                acc[mt] = __builtin_amdgcn_mfma_f32_16x16x32_f16(af, bf, acc[mt], 0, 0, 0);
            }
        }
    } else {
        const f16* brow1 = wih1 + (size_t)n * H_SZ;
        const f16* brow2 = whh1 + (size_t)n * H_SZ;
        const f16* h2prev = h2buf + prv * (B_SZ * H_SZ);
        // input part: h1[t-1] @ w_ih1^T
        #pragma unroll
        for (int it = 0; it < 16; ++it) {
            int k = p * 512 + it * 32 + q * 8;
            half8 bf = *(const half8*)(brow1 + k);
            #pragma unroll
            for (int mt = 0; mt < 4; ++mt) {
                half8 af = *(const half8*)(h1prev + (size_t)(mt * 16 + r16) * H_SZ + k);
                acc[mt] = __builtin_amdgcn_mfma_f32_16x16x32_f16(af, bf, acc[mt], 0, 0, 0);
            }
        }
        // recurrent part: h2[t-2] @ w_hh1^T
        #pragma unroll
        for (int it = 0; it < 16; ++it) {
            int k = p * 512 + it * 32 + q * 8;
            half8 bf = *(const half8*)(brow2 + k);
            #pragma unroll
            for (int mt = 0; mt < 4; ++mt) {
                half8 af = *(const half8*)(h2prev + (size_t)(mt * 16 + r16) * H_SZ + k);
                acc[mt] = __builtin_amdgcn_mfma_f32_16x16x32_f16(af, bf, acc[mt], 0, 0, 0);
            }
        }
    }

    // k-half reduction + gate assembly through LDS.
    // C/D layout: row (batch) = q*4 + reg, col (gate j) = r16.
    __shared__ float lds[2][4][64][16];
    #pragma unroll
    for (int mt = 0; mt < 4; ++mt)
        #pragma unroll
        for (int r = 0; r < 4; ++r)
            lds[p][g][mt * 16 + q * 4 + r][r16] = acc[mt][r];
    __syncthreads();

    const float* bias = layer ? bias1 : bias0;
    float* c = layer ? c1 : c0;
    f16* hnew = (layer ? h2buf : h1buf) + cur * (B_SZ * H_SZ);

    for (int e = tid; e < B_SZ * 16; e += 512) {
        int b = e >> 4, j = e & 15;
        int col = jb + j;
        float xi = lds[0][0][b][j] + lds[1][0][b][j] + bias[col];
        float xf = lds[0][1][b][j] + lds[1][1][b][j] + bias[H_SZ + col];
        float xg = lds[0][2][b][j] + lds[1][2][b][j] + bias[2 * H_SZ + col];
        float xo = lds[0][3][b][j] + lds[1][3][b][j] + bias[3 * H_SZ + col];
        float cold = c[b * H_SZ + col];
        float ii = sigf(xi), ff = sigf(xf), gg = tanhfast(xg), oo = sigf(xo);
        float cn = ff * cold + ii * gg;
        float hn = oo * tanhfast(cn);
        c[b * H_SZ + col] = cn;
        hnew[b * H_SZ + col] = (f16)hn;
        if (layer) h2all[(size_t)(s - 1) * (B_SZ * H_SZ) + b * H_SZ + col] = (f16)hn;
    }
}

// ---------------------------------------------------------------------------
// Output projection: out[b,t] = h2[t,b,:] . w_out + b_out
// ---------------------------------------------------------------------------
__global__ __launch_bounds__(256) void gemv_kernel(
    const f16* __restrict__ h2all, const float* __restrict__ wout,
    const float* __restrict__ bout, float* __restrict__ out)
{
    int t = blockIdx.x;
    int wave = threadIdx.x >> 6, lane = threadIdx.x & 63;
    float w[16];
    #pragma unroll
    for (int u = 0; u < 16; ++u) w[u] = wout[lane * 16 + u];
    float b0 = bout[0];
    for (int b = wave; b < B_SZ; b += 4) {
        const f16* hp = h2all + ((size_t)t * B_SZ + b) * H_SZ + lane * 16;
        float sum = 0.f;
        #pragma unroll
        for (int u = 0; u < 16; ++u) sum += (float)hp[u] * w[u];
        #pragma unroll
        for (int off = 32; off; off >>= 1) sum += __shfl_down(sum, off, 64);
        if (lane == 0) out[(size_t)b * T_SEQ + t] = sum + b0;
    }
}

// ---------------------------------------------------------------------------
extern "C" void kernel_launch(void* const* d_in, const int* in_sizes, int n_in,
                              void* d_out, int out_size, void* d_ws, size_t ws_size,
                              hipStream_t stream)
{
    const float* x    = (const float*)d_in[0];
    const float* wih0 = (const float*)d_in[1];
    const float* whh0 = (const float*)d_in[2];
    const float* bih0 = (const float*)d_in[3];
    const float* bhh0 = (const float*)d_in[4];
    const float* wih1 = (const float*)d_in[5];
    const float* whh1 = (const float*)d_in[6];
    const float* bih1 = (const float*)d_in[7];
    const float* bhh1 = (const float*)d_in[8];
    const float* wout = (const float*)d_in[9];
    const float* bout = (const float*)d_in[10];
    float* out = (float*)d_out;

    char* ws = (char*)d_ws;
    size_t off = 0;
    auto alloc = [&](size_t bytes) -> void* {
        void* p = ws + off;
        off += (bytes + 511) & ~(size_t)511;
        return p;
    };
    float* c0    = (float*)alloc(B_SZ * H_SZ * 4);
    float* c1    = (float*)alloc(B_SZ * H_SZ * 4);
    float* bias0 = (float*)alloc(4096 * 4);
    float* bias1 = (float*)alloc(4096 * 4);
    f16* h1buf = (f16*)alloc(2 * B_SZ * H_SZ * 2);
    f16* h2buf = (f16*)alloc(2 * B_SZ * H_SZ * 2);
    f16* wih0h = (f16*)alloc((size_t)4096 * 512 * 2);
    f16* whh0h = (f16*)alloc((size_t)4096 * 1024 * 2);
    f16* wih1h = (f16*)alloc((size_t)4096 * 1024 * 2);
    f16* whh1h = (f16*)alloc((size_t)4096 * 1024 * 2);
    f16* h2all = (f16*)alloc((size_t)T_SEQ * B_SZ * H_SZ * 2);

    // zero initial state (ws is poisoned 0xAA before every launch)
    hipMemsetAsync(c0, 0, B_SZ * H_SZ * 4, stream);
    hipMemsetAsync(c1, 0, B_SZ * H_SZ * 4, stream);
    hipMemsetAsync(h1buf, 0, 2 * B_SZ * H_SZ * 2, stream);
    hipMemsetAsync(h2buf, 0, 2 * B_SZ * H_SZ * 2, stream);

    convert_kernel<<<1024, 256, 0, stream>>>(wih0, whh0, wih1, whh1,
                                             bih0, bhh0, bih1, bhh1,
                                             wih0h, whh0h, wih1h, whh1h,
                                             bias0, bias1);

    for (int s = 0; s <= T_SEQ; ++s)
        step_kernel<<<128, 512, 0, stream>>>(x, wih0h, whh0h, wih1h, whh1h,
                                             bias0, bias1, h1buf, h2buf,
                                             c0, c1, h2all, s);

    gemv_kernel<<<T_SEQ, 256, 0, stream>>>(h2all, wout, bout, out);
}